// Round 10
// baseline (299.682 us; speedup 1.0000x reference)
//
#include <hip/hip_runtime.h>
#include <hip/hip_bf16.h>

#define N_NODES 50000
#define N_EDGES 800000
#define D 128
#define ALPHA 0.2f
#define NEG_INF -1e30f

#define KB_BLOCKS 3125                          // 1 edge per thread, exact
#define NSCAN_BLOCKS ((N_NODES + 255) / 256)   // 196
#define LDS_STRIDE 272                          // 16 rows x (256B + 16B pad)

typedef __attribute__((ext_vector_type(8))) short short8;
typedef __attribute__((ext_vector_type(4))) float floatx4;

__device__ __forceinline__ unsigned int f2bf(float v)
{
    __hip_bfloat16 b = __float2bfloat16(v);
    return (unsigned int)*reinterpret_cast<unsigned short*>(&b);
}
__device__ __forceinline__ float bf_lo(unsigned int u)
{
    return __uint_as_float(u << 16);
}
__device__ __forceinline__ float bf_hi(unsigned int u)
{
    return __uint_as_float(u & 0xFFFF0000u);
}

// ---- K0: zero deg + sync counters; block 0 computes w12 = {W@a1, W@a2}
__global__ __launch_bounds__(256) void k_prep(
    const float* __restrict__ W, const float* __restrict__ a,
    float* __restrict__ w12, int* __restrict__ deg, int* __restrict__ syncv)
{
    const int i = blockIdx.x * 256 + threadIdx.x;
    if (i < N_NODES) deg[i] = 0;
    if (i < 4) syncv[i] = 0;
    if (blockIdx.x == 0) {
        const int t = threadIdx.x;
        const int r = t & 127;
        const int which = t >> 7;
        const float* av = a + which * D;
        float acc = 0.f;
        #pragma unroll 8
        for (int j = 0; j < D; ++j)
            acc += W[(size_t)r * D + j] * av[j];
        w12[which * D + r] = acc;
    }
}

// ---- K1: fused per-16-row-tile kernel, 3125 blocks (exact):
//   (a) load x tile fp32, exact s1/s2 (16-lane xor-reduce), bf16 -> LDS
//   (b) per-wave B frags from W, even/odd column split
//   (c) 8x MFMA 16x16x32 bf16, packed u32 stores of hb
//   (d) deg count + per-edge rank (atomic return), 1 edge per thread
__global__ __launch_bounds__(256) void k_fused(
    const float* __restrict__ x, const float* __restrict__ W,
    const float* __restrict__ w12, const int* __restrict__ ei,
    unsigned short* __restrict__ hb, float* __restrict__ s1,
    float* __restrict__ s2, int* __restrict__ deg, int* __restrict__ rank)
{
    __shared__ unsigned char lds[16 * LDS_STRIDE];
    const int t = threadIdx.x;
    const int rowbase = blockIdx.x * 16;

    // (a) stage x: thread t -> row r=t>>4, col-group c=t&15 (8 cols)
    const int r = t >> 4;
    const int c = t & 15;
    const float* xp = x + (size_t)(rowbase + r) * D + c * 8;
    const float4 v0 = *(const float4*)(xp);
    const float4 v1 = *(const float4*)(xp + 4);

    // (b) B frags — issue independent of staging loads
    const int lane = t & 63;
    const int wv = t >> 6;
    const int q = lane >> 4;
    const int nIdx = lane & 15;
    const int n0 = wv * 32;
    short8 B[2][4];
    #pragma unroll
    for (int kt = 0; kt < 4; ++kt) {
        short8 be, bo;
        #pragma unroll
        for (int j = 0; j < 8; ++j) {
            const float* wp = W + (size_t)(kt * 32 + q * 8 + j) * D + n0 + 2 * nIdx;
            be[j] = (short)f2bf(wp[0]);
            bo[j] = (short)f2bf(wp[1]);
        }
        B[0][kt] = be;
        B[1][kt] = bo;
    }

    // (a cont.) s1/s2 exact fp32 partials + bf16 pack to LDS
    {
        const float* w1 = w12 + c * 8;
        const float* w2 = w12 + D + c * 8;
        float p1 = v0.x * w1[0] + v0.y * w1[1] + v0.z * w1[2] + v0.w * w1[3]
                 + v1.x * w1[4] + v1.y * w1[5] + v1.z * w1[6] + v1.w * w1[7];
        float p2 = v0.x * w2[0] + v0.y * w2[1] + v0.z * w2[2] + v0.w * w2[3]
                 + v1.x * w2[4] + v1.y * w2[5] + v1.z * w2[6] + v1.w * w2[7];
        #pragma unroll
        for (int mask = 8; mask >= 1; mask >>= 1) {
            p1 += __shfl_xor(p1, mask);
            p2 += __shfl_xor(p2, mask);
        }
        if (c == 0) { s1[rowbase + r] = p1; s2[rowbase + r] = p2; }

        uint4 pk;
        pk.x = f2bf(v0.x) | (f2bf(v0.y) << 16);
        pk.y = f2bf(v0.z) | (f2bf(v0.w) << 16);
        pk.z = f2bf(v1.x) | (f2bf(v1.y) << 16);
        pk.w = f2bf(v1.z) | (f2bf(v1.w) << 16);
        *(uint4*)(lds + r * LDS_STRIDE + c * 16) = pk;
    }
    __syncthreads();

    // (c) A frags from LDS: A[m=nIdx][k=kt*32+q*8+j] -> byte kt*64 + q*16
    const unsigned char* ab = lds + nIdx * LDS_STRIDE + q * 16;
    const short8 A0 = *(const short8*)(ab);
    const short8 A1 = *(const short8*)(ab + 64);
    const short8 A2 = *(const short8*)(ab + 128);
    const short8 A3 = *(const short8*)(ab + 192);

    floatx4 acc0 = {0.f, 0.f, 0.f, 0.f};
    floatx4 acc1 = {0.f, 0.f, 0.f, 0.f};
    acc0 = __builtin_amdgcn_mfma_f32_16x16x32_bf16(A0, B[0][0], acc0, 0, 0, 0);
    acc1 = __builtin_amdgcn_mfma_f32_16x16x32_bf16(A0, B[1][0], acc1, 0, 0, 0);
    acc0 = __builtin_amdgcn_mfma_f32_16x16x32_bf16(A1, B[0][1], acc0, 0, 0, 0);
    acc1 = __builtin_amdgcn_mfma_f32_16x16x32_bf16(A1, B[1][1], acc1, 0, 0, 0);
    acc0 = __builtin_amdgcn_mfma_f32_16x16x32_bf16(A2, B[0][2], acc0, 0, 0, 0);
    acc1 = __builtin_amdgcn_mfma_f32_16x16x32_bf16(A2, B[1][2], acc1, 0, 0, 0);
    acc0 = __builtin_amdgcn_mfma_f32_16x16x32_bf16(A3, B[0][3], acc0, 0, 0, 0);
    acc1 = __builtin_amdgcn_mfma_f32_16x16x32_bf16(A3, B[1][3], acc1, 0, 0, 0);

    // epilogue: acc0 = even col n0+2*nIdx, acc1 = odd col n0+2*nIdx+1
    #pragma unroll
    for (int i = 0; i < 4; ++i) {
        const int row = rowbase + q * 4 + i;
        const unsigned int pk = f2bf(acc0[i]) | (f2bf(acc1[i]) << 16);
        *(unsigned int*)(hb + (size_t)row * D + n0 + 2 * nIdx) = pk;
    }

    // (d) deg + rank: exactly one edge per thread (3125*256 == N_EDGES)
    const int e = blockIdx.x * 256 + t;
    rank[e] = atomicAdd(&deg[ei[N_EDGES + e]], 1);
}

__device__ __forceinline__ void online_combine(float& m, float& s,
                                               float om, float os)
{
    float nm = fmaxf(m, om);
    s = s * __expf(m - nm) + os * __expf(om - nm);
    m = nm;
}

// ---- K2: single-kernel exclusive scan of deg -> offs.
// 196 blocks (all co-resident, << 2048 capacity): local scan, publish block
// aggregate, grid barrier via device-scope atomic arrive+spin, then every
// block scans the 196 aggregates itself and writes its offs slice.
__global__ __launch_bounds__(256) void k_scan(
    const int* __restrict__ deg, int* __restrict__ offs,
    int* __restrict__ agg, int* __restrict__ cnt)
{
    __shared__ int sc[256];
    const int t = threadIdx.x;
    const int b = blockIdx.x;
    const int i = b * 256 + t;
    const int v = (i < N_NODES) ? deg[i] : 0;
    sc[t] = v;
    __syncthreads();
    #pragma unroll
    for (int off = 1; off < 256; off <<= 1) {
        int u = (t >= off) ? sc[t - off] : 0;
        __syncthreads();
        sc[t] += u;
        __syncthreads();
    }
    const int excl = sc[t] - v;          // exclusive within block
    if (t == 0) {
        __hip_atomic_store(&agg[b], sc[255], __ATOMIC_RELAXED,
                           __HIP_MEMORY_SCOPE_AGENT);
        __hip_atomic_fetch_add(cnt, 1, __ATOMIC_RELEASE,
                               __HIP_MEMORY_SCOPE_AGENT);
        while (__hip_atomic_load(cnt, __ATOMIC_ACQUIRE,
                                 __HIP_MEMORY_SCOPE_AGENT) < NSCAN_BLOCKS) {}
    }
    __syncthreads();

    int av = (t < NSCAN_BLOCKS)
        ? __hip_atomic_load(&agg[t], __ATOMIC_RELAXED, __HIP_MEMORY_SCOPE_AGENT)
        : 0;
    sc[t] = av;
    __syncthreads();
    #pragma unroll
    for (int off = 1; off < 256; off <<= 1) {
        int u = (t >= off) ? sc[t - off] : 0;
        __syncthreads();
        sc[t] += u;
        __syncthreads();
    }
    const int prefix = (b == 0) ? 0 : sc[b - 1];
    if (i < N_NODES) offs[i] = prefix + excl;
    if (b == 0 && t == 0) offs[N_NODES] = N_EDGES;
}

// ---- K3: atomic-free scatter of src into dst-sorted CSR
// (pos = offs[dst] + rank[e]) + online-softmax block reduction; the LAST
// block to finish folds the 3125 per-block (m,s) into global MZ.
__global__ __launch_bounds__(256) void k_bucket(
    const int* __restrict__ ei, const float* __restrict__ s1,
    const float* __restrict__ s2, const int* __restrict__ offs,
    const int* __restrict__ rank, unsigned int* __restrict__ csr,
    float* __restrict__ bm, float* __restrict__ bs, int* __restrict__ cnt,
    float* __restrict__ MZ)
{
    const int e = blockIdx.x * 256 + threadIdx.x;
    const int sN = ei[e];
    const int dN = ei[N_EDGES + e];
    csr[offs[dN] + rank[e]] = (unsigned int)sN;

    float v = s1[sN] + s2[dN];
    v = v > 0.f ? v : ALPHA * v;

    float m = v, s = 1.f;
    #pragma unroll
    for (int off = 32; off >= 1; off >>= 1) {
        float om = __shfl_down(m, off);
        float os = __shfl_down(s, off);
        online_combine(m, s, om, os);
    }
    __shared__ float rm[4], rs[4];
    __shared__ int lastFlag;
    const int wid = threadIdx.x >> 6;
    if ((threadIdx.x & 63) == 0) { rm[wid] = m; rs[wid] = s; }
    __syncthreads();
    if (threadIdx.x == 0) {
        #pragma unroll
        for (int w = 1; w < 4; ++w) online_combine(m, s, rm[w], rs[w]);
        __hip_atomic_store(&bm[blockIdx.x], m, __ATOMIC_RELAXED,
                           __HIP_MEMORY_SCOPE_AGENT);
        __hip_atomic_store(&bs[blockIdx.x], s, __ATOMIC_RELAXED,
                           __HIP_MEMORY_SCOPE_AGENT);
        const int done = __hip_atomic_fetch_add(cnt, 1, __ATOMIC_ACQ_REL,
                                                __HIP_MEMORY_SCOPE_AGENT);
        lastFlag = (done == KB_BLOCKS - 1);
    }
    __syncthreads();
    if (!lastFlag) return;

    // last block: reduce all 3125 (m,s) -> MZ
    float mm = NEG_INF, ss = 0.f;
    for (int j = threadIdx.x; j < KB_BLOCKS; j += 256) {
        const float om = __hip_atomic_load(&bm[j], __ATOMIC_RELAXED,
                                           __HIP_MEMORY_SCOPE_AGENT);
        const float os = __hip_atomic_load(&bs[j], __ATOMIC_RELAXED,
                                           __HIP_MEMORY_SCOPE_AGENT);
        online_combine(mm, ss, om, os);
    }
    #pragma unroll
    for (int off = 32; off >= 1; off >>= 1) {
        float om = __shfl_down(mm, off);
        float os = __shfl_down(ss, off);
        online_combine(mm, ss, om, os);
    }
    if ((threadIdx.x & 63) == 0) { rm[wid] = mm; rs[wid] = ss; }
    __syncthreads();
    if (threadIdx.x == 0) {
        #pragma unroll
        for (int w = 1; w < 4; ++w) online_combine(mm, ss, rm[w], rs[w]);
        MZ[0] = mm;
        MZ[1] = ss;
    }
}

// ---- K4: gather. One wave per dst node; lane loads ONE csr src (coalesced),
// recomputes exact fp32 score + ONE exp; inner loop broadcasts (src, att)
// via uniform-index shfl with 8 independent hb row loads in flight.
__global__ __launch_bounds__(256) void k_gather(
    const unsigned int* __restrict__ csr, const int* __restrict__ offs,
    const float* __restrict__ s1, const float* __restrict__ s2,
    const unsigned short* __restrict__ hb, const float* __restrict__ MZ,
    float* __restrict__ out)
{
    const int node = (blockIdx.x * blockDim.x + threadIdx.x) >> 6;
    if (node >= N_NODES) return;
    const int lane = threadIdx.x & 63;
    const float M = MZ[0];
    const float invZ = 1.0f / MZ[1];
    const float s2n = s2[node];
    const int beg = offs[node];
    const int end = offs[node + 1];

    float a0 = 0.f, a1 = 0.f, b0 = 0.f, b1 = 0.f;
    float c0 = 0.f, c1 = 0.f, d0 = 0.f, d1 = 0.f;
    float e0 = 0.f, e1 = 0.f, f0 = 0.f, f1 = 0.f;
    float g0 = 0.f, g1 = 0.f, h0 = 0.f, h1 = 0.f;

    for (int cb = beg; cb < end; cb += 64) {
        const int n = min(64, end - cb);
        const int srcl = (cb + lane < end) ? (int)csr[cb + lane] : 0;
        float v = s1[srcl] + s2n;
        v = v > 0.f ? v : ALPHA * v;
        const float attl = __expf(v - M) * invZ;

        int j = 0;
        for (; j + 7 < n; j += 8) {
            const int i0 = __shfl(srcl, j);
            const int i1 = __shfl(srcl, j + 1);
            const int i2 = __shfl(srcl, j + 2);
            const int i3 = __shfl(srcl, j + 3);
            const int i4 = __shfl(srcl, j + 4);
            const int i5 = __shfl(srcl, j + 5);
            const int i6 = __shfl(srcl, j + 6);
            const int i7 = __shfl(srcl, j + 7);
            const float w0 = __shfl(attl, j);
            const float w1 = __shfl(attl, j + 1);
            const float w2 = __shfl(attl, j + 2);
            const float w3 = __shfl(attl, j + 3);
            const float w4 = __shfl(attl, j + 4);
            const float w5 = __shfl(attl, j + 5);
            const float w6 = __shfl(attl, j + 6);
            const float w7 = __shfl(attl, j + 7);
            const unsigned int u0 = *(const unsigned int*)(hb + (size_t)i0 * D + lane * 2);
            const unsigned int u1 = *(const unsigned int*)(hb + (size_t)i1 * D + lane * 2);
            const unsigned int u2 = *(const unsigned int*)(hb + (size_t)i2 * D + lane * 2);
            const unsigned int u3 = *(const unsigned int*)(hb + (size_t)i3 * D + lane * 2);
            const unsigned int u4 = *(const unsigned int*)(hb + (size_t)i4 * D + lane * 2);
            const unsigned int u5 = *(const unsigned int*)(hb + (size_t)i5 * D + lane * 2);
            const unsigned int u6 = *(const unsigned int*)(hb + (size_t)i6 * D + lane * 2);
            const unsigned int u7 = *(const unsigned int*)(hb + (size_t)i7 * D + lane * 2);
            a0 += w0 * bf_lo(u0); a1 += w0 * bf_hi(u0);
            b0 += w1 * bf_lo(u1); b1 += w1 * bf_hi(u1);
            c0 += w2 * bf_lo(u2); c1 += w2 * bf_hi(u2);
            d0 += w3 * bf_lo(u3); d1 += w3 * bf_hi(u3);
            e0 += w4 * bf_lo(u4); e1 += w4 * bf_hi(u4);
            f0 += w5 * bf_lo(u5); f1 += w5 * bf_hi(u5);
            g0 += w6 * bf_lo(u6); g1 += w6 * bf_hi(u6);
            h0 += w7 * bf_lo(u7); h1 += w7 * bf_hi(u7);
        }
        for (; j + 3 < n; j += 4) {
            const int i0 = __shfl(srcl, j);
            const int i1 = __shfl(srcl, j + 1);
            const int i2 = __shfl(srcl, j + 2);
            const int i3 = __shfl(srcl, j + 3);
            const float w0 = __shfl(attl, j);
            const float w1 = __shfl(attl, j + 1);
            const float w2 = __shfl(attl, j + 2);
            const float w3 = __shfl(attl, j + 3);
            const unsigned int u0 = *(const unsigned int*)(hb + (size_t)i0 * D + lane * 2);
            const unsigned int u1 = *(const unsigned int*)(hb + (size_t)i1 * D + lane * 2);
            const unsigned int u2 = *(const unsigned int*)(hb + (size_t)i2 * D + lane * 2);
            const unsigned int u3 = *(const unsigned int*)(hb + (size_t)i3 * D + lane * 2);
            a0 += w0 * bf_lo(u0); a1 += w0 * bf_hi(u0);
            b0 += w1 * bf_lo(u1); b1 += w1 * bf_hi(u1);
            c0 += w2 * bf_lo(u2); c1 += w2 * bf_hi(u2);
            d0 += w3 * bf_lo(u3); d1 += w3 * bf_hi(u3);
        }
        for (; j < n; ++j) {
            const int i0 = __shfl(srcl, j);
            const float w0 = __shfl(attl, j);
            const unsigned int u0 = *(const unsigned int*)(hb + (size_t)i0 * D + lane * 2);
            a0 += w0 * bf_lo(u0); a1 += w0 * bf_hi(u0);
        }
    }
    float2 r;
    r.x = ((a0 + b0) + (c0 + d0)) + ((e0 + f0) + (g0 + h0));
    r.y = ((a1 + b1) + (c1 + d1)) + ((e1 + f1) + (g1 + h1));
    *(float2*)(out + (size_t)node * D + lane * 2) = r;
}

extern "C" void kernel_launch(void* const* d_in, const int* in_sizes, int n_in,
                              void* d_out, int out_size, void* d_ws, size_t ws_size,
                              hipStream_t stream)
{
    const float* x = (const float*)d_in[0];
    const float* W = (const float*)d_in[1];
    const float* a = (const float*)d_in[2];
    const int* ei = (const int*)d_in[3];
    float* out = (float*)d_out;

    char* wsb = (char*)d_ws;
    unsigned int* csr = (unsigned int*)wsb;                        // 3.2 MB
    unsigned short* hb = (unsigned short*)(wsb + (size_t)N_EDGES * 4); // 12.8 MB
    int* rank     = (int*)((char*)hb + (size_t)N_NODES * D * 2);   // 3.2 MB
    float* s1     = (float*)(rank + N_EDGES);                      // 50,000
    float* s2     = s1 + N_NODES;                                  // 50,000
    int*   deg    = (int*)(s2 + N_NODES);                          // 50,000
    int*   offs   = deg + N_NODES;                                 // 50,001
    int*   agg    = offs + N_NODES + 1;                            // 196
    int*   syncv  = agg + NSCAN_BLOCKS;                            // 4
    float* w12    = (float*)(syncv + 4);                           // 256
    float* bm     = w12 + 2 * D;                                   // 3125
    float* bs     = bm + KB_BLOCKS;                                // 3125
    float* MZ     = bs + KB_BLOCKS;                                // 2

    k_prep<<<NSCAN_BLOCKS, 256, 0, stream>>>(W, a, w12, deg, syncv);
    k_fused<<<N_NODES / 16, 256, 0, stream>>>(x, W, w12, ei, hb, s1, s2,
                                              deg, rank);
    k_scan<<<NSCAN_BLOCKS, 256, 0, stream>>>(deg, offs, agg, syncv + 0);
    k_bucket<<<KB_BLOCKS, 256, 0, stream>>>(ei, s1, s2, offs, rank, csr,
                                            bm, bs, syncv + 1, MZ);
    k_gather<<<(N_NODES * 64 + 255) / 256, 256, 0, stream>>>(
        csr, offs, s1, s2, hb, MZ, out);
}

// Round 11
// 186.495 us; speedup vs baseline: 1.6069x; 1.6069x over previous
//
#include <hip/hip_runtime.h>
#include <hip/hip_bf16.h>

#define N_NODES 50000
#define N_EDGES 800000
#define D 128
#define ALPHA 0.2f
#define NEG_INF -1e30f

#define KB_BLOCKS 3125                          // 1 edge per thread, exact
#define NSCAN_BLOCKS ((N_NODES + 255) / 256)   // 196
#define LDS_STRIDE 272                          // 16 rows x (256B + 16B pad)

typedef __attribute__((ext_vector_type(8))) short short8;
typedef __attribute__((ext_vector_type(4))) float floatx4;

__device__ __forceinline__ unsigned int f2bf(float v)
{
    __hip_bfloat16 b = __float2bfloat16(v);
    return (unsigned int)*reinterpret_cast<unsigned short*>(&b);
}
__device__ __forceinline__ float bf_lo(unsigned int u)
{
    return __uint_as_float(u << 16);
}
__device__ __forceinline__ float bf_hi(unsigned int u)
{
    return __uint_as_float(u & 0xFFFF0000u);
}

// ---- K0: zero deg; block 0 computes w12 = {W@a1, W@a2}. Plain stores only —
// the kernel boundary is the (free) device-wide fence. No in-kernel
// release atomics: on CDNA4 each agent-scope release = L2 writeback (R10:
// 3125 of them cost 130 us).
__global__ __launch_bounds__(256) void k_prep(
    const float* __restrict__ W, const float* __restrict__ a,
    float* __restrict__ w12, int* __restrict__ deg)
{
    const int i = blockIdx.x * 256 + threadIdx.x;
    if (i < N_NODES) deg[i] = 0;
    if (blockIdx.x == 0) {
        const int t = threadIdx.x;
        const int r = t & 127;
        const int which = t >> 7;
        const float* av = a + which * D;
        float acc = 0.f;
        #pragma unroll 8
        for (int j = 0; j < D; ++j)
            acc += W[(size_t)r * D + j] * av[j];
        w12[which * D + r] = acc;
    }
}

// ---- K1: fused per-16-row-tile kernel, 3125 blocks (exact):
//   (a) load x tile fp32, exact s1/s2 (16-lane xor-reduce), bf16 -> LDS
//   (b) per-wave B frags from W, even/odd column split
//   (c) 8x MFMA 16x16x32 bf16, packed u32 stores of hb
//   (d) deg count + per-edge rank (atomic return), 1 edge per thread
__global__ __launch_bounds__(256) void k_fused(
    const float* __restrict__ x, const float* __restrict__ W,
    const float* __restrict__ w12, const int* __restrict__ ei,
    unsigned short* __restrict__ hb, float* __restrict__ s1,
    float* __restrict__ s2, int* __restrict__ deg, int* __restrict__ rank)
{
    __shared__ unsigned char lds[16 * LDS_STRIDE];
    const int t = threadIdx.x;
    const int rowbase = blockIdx.x * 16;

    // (a) stage x: thread t -> row r=t>>4, col-group c=t&15 (8 cols)
    const int r = t >> 4;
    const int c = t & 15;
    const float* xp = x + (size_t)(rowbase + r) * D + c * 8;
    const float4 v0 = *(const float4*)(xp);
    const float4 v1 = *(const float4*)(xp + 4);

    // (b) B frags — issue independent of staging loads
    const int lane = t & 63;
    const int wv = t >> 6;
    const int q = lane >> 4;
    const int nIdx = lane & 15;
    const int n0 = wv * 32;
    short8 B[2][4];
    #pragma unroll
    for (int kt = 0; kt < 4; ++kt) {
        short8 be, bo;
        #pragma unroll
        for (int j = 0; j < 8; ++j) {
            const float* wp = W + (size_t)(kt * 32 + q * 8 + j) * D + n0 + 2 * nIdx;
            be[j] = (short)f2bf(wp[0]);
            bo[j] = (short)f2bf(wp[1]);
        }
        B[0][kt] = be;
        B[1][kt] = bo;
    }

    // (a cont.) s1/s2 exact fp32 partials + bf16 pack to LDS
    {
        const float* w1 = w12 + c * 8;
        const float* w2 = w12 + D + c * 8;
        float p1 = v0.x * w1[0] + v0.y * w1[1] + v0.z * w1[2] + v0.w * w1[3]
                 + v1.x * w1[4] + v1.y * w1[5] + v1.z * w1[6] + v1.w * w1[7];
        float p2 = v0.x * w2[0] + v0.y * w2[1] + v0.z * w2[2] + v0.w * w2[3]
                 + v1.x * w2[4] + v1.y * w2[5] + v1.z * w2[6] + v1.w * w2[7];
        #pragma unroll
        for (int mask = 8; mask >= 1; mask >>= 1) {
            p1 += __shfl_xor(p1, mask);
            p2 += __shfl_xor(p2, mask);
        }
        if (c == 0) { s1[rowbase + r] = p1; s2[rowbase + r] = p2; }

        uint4 pk;
        pk.x = f2bf(v0.x) | (f2bf(v0.y) << 16);
        pk.y = f2bf(v0.z) | (f2bf(v0.w) << 16);
        pk.z = f2bf(v1.x) | (f2bf(v1.y) << 16);
        pk.w = f2bf(v1.z) | (f2bf(v1.w) << 16);
        *(uint4*)(lds + r * LDS_STRIDE + c * 16) = pk;
    }
    __syncthreads();

    // (c) A frags from LDS: A[m=nIdx][k=kt*32+q*8+j] -> byte kt*64 + q*16
    const unsigned char* ab = lds + nIdx * LDS_STRIDE + q * 16;
    const short8 A0 = *(const short8*)(ab);
    const short8 A1 = *(const short8*)(ab + 64);
    const short8 A2 = *(const short8*)(ab + 128);
    const short8 A3 = *(const short8*)(ab + 192);

    floatx4 acc0 = {0.f, 0.f, 0.f, 0.f};
    floatx4 acc1 = {0.f, 0.f, 0.f, 0.f};
    acc0 = __builtin_amdgcn_mfma_f32_16x16x32_bf16(A0, B[0][0], acc0, 0, 0, 0);
    acc1 = __builtin_amdgcn_mfma_f32_16x16x32_bf16(A0, B[1][0], acc1, 0, 0, 0);
    acc0 = __builtin_amdgcn_mfma_f32_16x16x32_bf16(A1, B[0][1], acc0, 0, 0, 0);
    acc1 = __builtin_amdgcn_mfma_f32_16x16x32_bf16(A1, B[1][1], acc1, 0, 0, 0);
    acc0 = __builtin_amdgcn_mfma_f32_16x16x32_bf16(A2, B[0][2], acc0, 0, 0, 0);
    acc1 = __builtin_amdgcn_mfma_f32_16x16x32_bf16(A2, B[1][2], acc1, 0, 0, 0);
    acc0 = __builtin_amdgcn_mfma_f32_16x16x32_bf16(A3, B[0][3], acc0, 0, 0, 0);
    acc1 = __builtin_amdgcn_mfma_f32_16x16x32_bf16(A3, B[1][3], acc1, 0, 0, 0);

    // epilogue: acc0 = even col n0+2*nIdx, acc1 = odd col n0+2*nIdx+1
    #pragma unroll
    for (int i = 0; i < 4; ++i) {
        const int row = rowbase + q * 4 + i;
        const unsigned int pk = f2bf(acc0[i]) | (f2bf(acc1[i]) << 16);
        *(unsigned int*)(hb + (size_t)row * D + n0 + 2 * nIdx) = pk;
    }

    // (d) deg + rank: exactly one edge per thread (3125*256 == N_EDGES)
    const int e = blockIdx.x * 256 + t;
    rank[e] = atomicAdd(&deg[ei[N_EDGES + e]], 1);
}

__device__ __forceinline__ void online_combine(float& m, float& s,
                                               float om, float os)
{
    float nm = fmaxf(m, om);
    s = s * __expf(m - nm) + os * __expf(om - nm);
    m = nm;
}

// ---- two-level scan: A) block sums, B) scan of partials, C) local scan+add
__global__ __launch_bounds__(256) void k_scan_a(
    const int* __restrict__ deg, int* __restrict__ partials)
{
    const int i = blockIdx.x * 256 + threadIdx.x;
    int v = (i < N_NODES) ? deg[i] : 0;
    #pragma unroll
    for (int off = 32; off >= 1; off >>= 1) v += __shfl_down(v, off);
    __shared__ int ws[4];
    if ((threadIdx.x & 63) == 0) ws[threadIdx.x >> 6] = v;
    __syncthreads();
    if (threadIdx.x == 0)
        partials[blockIdx.x] = ws[0] + ws[1] + ws[2] + ws[3];
}

__global__ __launch_bounds__(256) void k_scan_b(
    const int* __restrict__ partials, int* __restrict__ partialOffs,
    int* __restrict__ offs)
{
    __shared__ int sc[256];
    const int t = threadIdx.x;
    int v = (t < NSCAN_BLOCKS) ? partials[t] : 0;
    sc[t] = v;
    __syncthreads();
    #pragma unroll
    for (int off = 1; off < 256; off <<= 1) {
        int u = (t >= off) ? sc[t - off] : 0;
        __syncthreads();
        sc[t] += u;
        __syncthreads();
    }
    if (t < NSCAN_BLOCKS) partialOffs[t] = sc[t] - v;   // exclusive
    if (t == 255) offs[N_NODES] = sc[255];              // == N_EDGES
}

__global__ __launch_bounds__(256) void k_scan_c(
    const int* __restrict__ deg, const int* __restrict__ partialOffs,
    int* __restrict__ offs)
{
    __shared__ int sc[256];
    const int t = threadIdx.x;
    const int i = blockIdx.x * 256 + t;
    const int v = (i < N_NODES) ? deg[i] : 0;
    sc[t] = v;
    __syncthreads();
    #pragma unroll
    for (int off = 1; off < 256; off <<= 1) {
        int u = (t >= off) ? sc[t - off] : 0;
        __syncthreads();
        sc[t] += u;
        __syncthreads();
    }
    if (i < N_NODES)
        offs[i] = partialOffs[blockIdx.x] + sc[t] - v;  // exclusive
}

// ---- K-bucket: atomic-free scatter of src into dst-sorted CSR
// (pos = offs[dst] + rank[e]) + online-softmax block reduction.
__global__ __launch_bounds__(256) void k_bucket(
    const int* __restrict__ ei, const float* __restrict__ s1,
    const float* __restrict__ s2, const int* __restrict__ offs,
    const int* __restrict__ rank, unsigned int* __restrict__ csr,
    float* __restrict__ bm, float* __restrict__ bs)
{
    const int e = blockIdx.x * 256 + threadIdx.x;
    const int sN = ei[e];
    const int dN = ei[N_EDGES + e];
    csr[offs[dN] + rank[e]] = (unsigned int)sN;

    float v = s1[sN] + s2[dN];
    v = v > 0.f ? v : ALPHA * v;

    float m = v, s = 1.f;
    #pragma unroll
    for (int off = 32; off >= 1; off >>= 1) {
        float om = __shfl_down(m, off);
        float os = __shfl_down(s, off);
        online_combine(m, s, om, os);
    }
    __shared__ float rm[4], rs[4];
    const int wid = threadIdx.x >> 6;
    if ((threadIdx.x & 63) == 0) { rm[wid] = m; rs[wid] = s; }
    __syncthreads();
    if (threadIdx.x == 0) {
        #pragma unroll
        for (int w = 1; w < 4; ++w) online_combine(m, s, rm[w], rs[w]);
        bm[blockIdx.x] = m;
        bs[blockIdx.x] = s;
    }
}

// ---- reduce per-block (m,s) -> global (M, Z)
__global__ __launch_bounds__(256) void k_reduce_mz(
    const float* __restrict__ bm, const float* __restrict__ bs,
    float* __restrict__ MZ)
{
    float m = NEG_INF, s = 0.f;
    for (int i = threadIdx.x; i < KB_BLOCKS; i += 256)
        online_combine(m, s, bm[i], bs[i]);
    #pragma unroll
    for (int off = 32; off >= 1; off >>= 1) {
        float om = __shfl_down(m, off);
        float os = __shfl_down(s, off);
        online_combine(m, s, om, os);
    }
    __shared__ float rm[4], rs[4];
    const int wid = threadIdx.x >> 6;
    if ((threadIdx.x & 63) == 0) { rm[wid] = m; rs[wid] = s; }
    __syncthreads();
    if (threadIdx.x == 0) {
        #pragma unroll
        for (int w = 1; w < 4; ++w) online_combine(m, s, rm[w], rs[w]);
        MZ[0] = m;
        MZ[1] = s;
    }
}

// ---- K-gather: one wave per dst node; lane loads ONE csr src (coalesced),
// recomputes exact fp32 score + ONE exp; inner loop broadcasts (src, att)
// via uniform-index shfl with 8 independent hb row loads in flight.
__global__ __launch_bounds__(256) void k_gather(
    const unsigned int* __restrict__ csr, const int* __restrict__ offs,
    const float* __restrict__ s1, const float* __restrict__ s2,
    const unsigned short* __restrict__ hb, const float* __restrict__ MZ,
    float* __restrict__ out)
{
    const int node = (blockIdx.x * blockDim.x + threadIdx.x) >> 6;
    if (node >= N_NODES) return;
    const int lane = threadIdx.x & 63;
    const float M = MZ[0];
    const float invZ = 1.0f / MZ[1];
    const float s2n = s2[node];
    const int beg = offs[node];
    const int end = offs[node + 1];

    float a0 = 0.f, a1 = 0.f, b0 = 0.f, b1 = 0.f;
    float c0 = 0.f, c1 = 0.f, d0 = 0.f, d1 = 0.f;
    float e0 = 0.f, e1 = 0.f, f0 = 0.f, f1 = 0.f;
    float g0 = 0.f, g1 = 0.f, h0 = 0.f, h1 = 0.f;

    for (int cb = beg; cb < end; cb += 64) {
        const int n = min(64, end - cb);
        const int srcl = (cb + lane < end) ? (int)csr[cb + lane] : 0;
        float v = s1[srcl] + s2n;
        v = v > 0.f ? v : ALPHA * v;
        const float attl = __expf(v - M) * invZ;

        int j = 0;
        for (; j + 7 < n; j += 8) {
            const int i0 = __shfl(srcl, j);
            const int i1 = __shfl(srcl, j + 1);
            const int i2 = __shfl(srcl, j + 2);
            const int i3 = __shfl(srcl, j + 3);
            const int i4 = __shfl(srcl, j + 4);
            const int i5 = __shfl(srcl, j + 5);
            const int i6 = __shfl(srcl, j + 6);
            const int i7 = __shfl(srcl, j + 7);
            const float w0 = __shfl(attl, j);
            const float w1 = __shfl(attl, j + 1);
            const float w2 = __shfl(attl, j + 2);
            const float w3 = __shfl(attl, j + 3);
            const float w4 = __shfl(attl, j + 4);
            const float w5 = __shfl(attl, j + 5);
            const float w6 = __shfl(attl, j + 6);
            const float w7 = __shfl(attl, j + 7);
            const unsigned int u0 = *(const unsigned int*)(hb + (size_t)i0 * D + lane * 2);
            const unsigned int u1 = *(const unsigned int*)(hb + (size_t)i1 * D + lane * 2);
            const unsigned int u2 = *(const unsigned int*)(hb + (size_t)i2 * D + lane * 2);
            const unsigned int u3 = *(const unsigned int*)(hb + (size_t)i3 * D + lane * 2);
            const unsigned int u4 = *(const unsigned int*)(hb + (size_t)i4 * D + lane * 2);
            const unsigned int u5 = *(const unsigned int*)(hb + (size_t)i5 * D + lane * 2);
            const unsigned int u6 = *(const unsigned int*)(hb + (size_t)i6 * D + lane * 2);
            const unsigned int u7 = *(const unsigned int*)(hb + (size_t)i7 * D + lane * 2);
            a0 += w0 * bf_lo(u0); a1 += w0 * bf_hi(u0);
            b0 += w1 * bf_lo(u1); b1 += w1 * bf_hi(u1);
            c0 += w2 * bf_lo(u2); c1 += w2 * bf_hi(u2);
            d0 += w3 * bf_lo(u3); d1 += w3 * bf_hi(u3);
            e0 += w4 * bf_lo(u4); e1 += w4 * bf_hi(u4);
            f0 += w5 * bf_lo(u5); f1 += w5 * bf_hi(u5);
            g0 += w6 * bf_lo(u6); g1 += w6 * bf_hi(u6);
            h0 += w7 * bf_lo(u7); h1 += w7 * bf_hi(u7);
        }
        for (; j + 3 < n; j += 4) {
            const int i0 = __shfl(srcl, j);
            const int i1 = __shfl(srcl, j + 1);
            const int i2 = __shfl(srcl, j + 2);
            const int i3 = __shfl(srcl, j + 3);
            const float w0 = __shfl(attl, j);
            const float w1 = __shfl(attl, j + 1);
            const float w2 = __shfl(attl, j + 2);
            const float w3 = __shfl(attl, j + 3);
            const unsigned int u0 = *(const unsigned int*)(hb + (size_t)i0 * D + lane * 2);
            const unsigned int u1 = *(const unsigned int*)(hb + (size_t)i1 * D + lane * 2);
            const unsigned int u2 = *(const unsigned int*)(hb + (size_t)i2 * D + lane * 2);
            const unsigned int u3 = *(const unsigned int*)(hb + (size_t)i3 * D + lane * 2);
            a0 += w0 * bf_lo(u0); a1 += w0 * bf_hi(u0);
            b0 += w1 * bf_lo(u1); b1 += w1 * bf_hi(u1);
            c0 += w2 * bf_lo(u2); c1 += w2 * bf_hi(u2);
            d0 += w3 * bf_lo(u3); d1 += w3 * bf_hi(u3);
        }
        for (; j < n; ++j) {
            const int i0 = __shfl(srcl, j);
            const float w0 = __shfl(attl, j);
            const unsigned int u0 = *(const unsigned int*)(hb + (size_t)i0 * D + lane * 2);
            a0 += w0 * bf_lo(u0); a1 += w0 * bf_hi(u0);
        }
    }
    float2 r;
    r.x = ((a0 + b0) + (c0 + d0)) + ((e0 + f0) + (g0 + h0));
    r.y = ((a1 + b1) + (c1 + d1)) + ((e1 + f1) + (g1 + h1));
    *(float2*)(out + (size_t)node * D + lane * 2) = r;
}

extern "C" void kernel_launch(void* const* d_in, const int* in_sizes, int n_in,
                              void* d_out, int out_size, void* d_ws, size_t ws_size,
                              hipStream_t stream)
{
    const float* x = (const float*)d_in[0];
    const float* W = (const float*)d_in[1];
    const float* a = (const float*)d_in[2];
    const int* ei = (const int*)d_in[3];
    float* out = (float*)d_out;

    char* wsb = (char*)d_ws;
    unsigned int* csr = (unsigned int*)wsb;                        // 3.2 MB
    unsigned short* hb = (unsigned short*)(wsb + (size_t)N_EDGES * 4); // 12.8 MB
    int* rank     = (int*)((char*)hb + (size_t)N_NODES * D * 2);   // 3.2 MB
    float* s1     = (float*)(rank + N_EDGES);                      // 50,000
    float* s2     = s1 + N_NODES;                                  // 50,000
    int*   deg    = (int*)(s2 + N_NODES);                          // 50,000
    int*   offs   = deg + N_NODES;                                 // 50,001
    int*   partials    = offs + N_NODES + 1;                       // 196
    int*   partialOffs = partials + NSCAN_BLOCKS;                  // 196
    float* w12    = (float*)(partialOffs + NSCAN_BLOCKS);          // 256
    float* bm     = w12 + 2 * D;                                   // 3125
    float* bs     = bm + KB_BLOCKS;                                // 3125
    float* MZ     = bs + KB_BLOCKS;                                // 2

    k_prep<<<NSCAN_BLOCKS, 256, 0, stream>>>(W, a, w12, deg);
    k_fused<<<N_NODES / 16, 256, 0, stream>>>(x, W, w12, ei, hb, s1, s2,
                                              deg, rank);
    k_scan_a<<<NSCAN_BLOCKS, 256, 0, stream>>>(deg, partials);
    k_scan_b<<<1, 256, 0, stream>>>(partials, partialOffs, offs);
    k_scan_c<<<NSCAN_BLOCKS, 256, 0, stream>>>(deg, partialOffs, offs);
    k_bucket<<<KB_BLOCKS, 256, 0, stream>>>(ei, s1, s2, offs, rank, csr,
                                            bm, bs);
    k_reduce_mz<<<1, 256, 0, stream>>>(bm, bs, MZ);
    k_gather<<<(N_NODES * 64 + 255) / 256, 256, 0, stream>>>(
        csr, offs, s1, s2, hb, MZ, out);
}